// Round 5
// baseline (377.137 us; speedup 1.0000x reference)
//
#include <hip/hip_runtime.h>
#include <math.h>

// Morphological opening, 10x10 flat kernel, SAME pad (window [i-4, i+5]).
// NHWC fp32 [16,512,512,8]. Two fused kernels:
//   erosion  (min): in -> ws      dilation (max): ws -> out (pads -inf)
// Per block (24x32 px output tile):
//   phase 1: H-op, GLOBAL->LDS, coalesced lanes over 82 f4 cols, 17 row-taps
//            -> run of 8 output rows (prefix/suffix trick).
//   phase 2: W-op, LDS->GLOBAL, 17 col-taps -> run of 8 px.
// TH=24 -> LDS 24*83*16 = 31,872 B -> 5 blocks/CU (20 waves/CU), vs R4's
// 42.5 KB -> 3 blocks/CU. Latency-bound regime: throughput ~ resident waves
// x in-flight loads; this raises potential in-flight bytes/CU 236->334 KB.

#define W_F4   1024              // 512 px * 2 f4 (8 ch)
#define IMG_F4 (512 * W_F4)
#define TH     24                // output rows per tile
#define TW     32                // output px per tile
#define MCOLS  82                // (TW + 9) px * 2 f4
#define S_M    83                // LDS row stride (odd -> bank-friendly)

__device__ __forceinline__ float4 f4min(float4 a, float4 b) {
    return make_float4(fminf(a.x,b.x), fminf(a.y,b.y), fminf(a.z,b.z), fminf(a.w,b.w));
}
__device__ __forceinline__ float4 f4max(float4 a, float4 b) {
    return make_float4(fmaxf(a.x,b.x), fmaxf(a.y,b.y), fmaxf(a.z,b.z), fmaxf(a.w,b.w));
}
template <bool IS_MIN>
__device__ __forceinline__ float4 f4op(float4 a, float4 b) {
    return IS_MIN ? f4min(a, b) : f4max(a, b);
}

template <bool IS_MIN>
__global__ __launch_bounds__(256, 5) void morph(const float4* __restrict__ in,
                                                float4* __restrict__ out) {
    __shared__ float4 sM[TH * S_M];      // 24*83*16 = 31,872 B -> 5 blocks/CU

    const float  IDENT  = IS_MIN ? INFINITY : -INFINITY;
    const float4 ident4 = make_float4(IDENT, IDENT, IDENT, IDENT);

    const int t  = threadIdx.x;
    const int h0 = blockIdx.y * TH;      // may reach 504 (ragged last band)
    const int w0 = blockIdx.x * TW;

    const float4* img  = in  + (size_t)blockIdx.z * IMG_F4;
    float4*       oimg = out + (size_t)blockIdx.z * IMG_F4;

    // ---- phase 1: H-op, global -> sM.  246 tasks: c in [0,82), p in [0,3) ----
    if (t < 3 * MCOLS) {
        const int c = t % MCOLS;         // f4 col within M (lanes contiguous)
        const int p = t / MCOLS;         // run of 8 output rows: p*8 + i
        const int colf4 = w0 * 2 - 8 + c;
        const bool colok = (colf4 >= 0) & (colf4 < W_F4);

        float4 v[17];
#pragma unroll
        for (int q = 0; q < 17; q++) {   // input rows h0 + p*8 - 4 + q
            int h = h0 + p * 8 - 4 + q;
            bool ok = colok & (h >= 0) & (h < 512);
            v[q] = ok ? img[(size_t)h * W_F4 + colf4] : ident4;
        }
        float4 L[9]; L[8] = v[8];
#pragma unroll
        for (int i = 7; i >= 0; i--) L[i] = f4op<IS_MIN>(v[i], L[i + 1]);
        float4 rr = v[9];
#pragma unroll
        for (int i = 0; i < 8; i++) {
            if (i > 0) rr = f4op<IS_MIN>(rr, v[9 + i]);
            sM[(p * 8 + i) * S_M + c] = f4op<IS_MIN>(L[i], rr);
        }
    }
    __syncthreads();

    // ---- phase 2: W-op, sM -> global.  192 tasks: c4 x 24 rows x 4 runs ----
    if (t < 2 * TH * (TW / 8)) {
        const int c4 = t & 1;
        const int r  = (t >> 1) % TH;
        const int p  = (t >> 1) / TH;    // 0..3, run of 8 output px
        const int hr = h0 + r;

        if (hr < 512) {                  // ragged last band: skip dead rows
            float4 v[17];
#pragma unroll
            for (int q = 0; q < 17; q++) // M px p*8+q  (<= 40 -> f4 <= 81)
                v[q] = sM[r * S_M + (p * 8 + q) * 2 + c4];
            float4 L[9]; L[8] = v[8];
#pragma unroll
            for (int i = 7; i >= 0; i--) L[i] = f4op<IS_MIN>(v[i], L[i + 1]);
            float4 rr = v[9];
            const size_t rowbase = (size_t)hr * W_F4 + (size_t)w0 * 2 + c4;
#pragma unroll
            for (int i = 0; i < 8; i++) {
                if (i > 0) rr = f4op<IS_MIN>(rr, v[9 + i]);
                oimg[rowbase + (p * 8 + i) * 2] = f4op<IS_MIN>(L[i], rr);
            }
        }
    }
}

extern "C" void kernel_launch(void* const* d_in, const int* in_sizes, int n_in,
                              void* d_out, int out_size, void* d_ws, size_t ws_size,
                              hipStream_t stream) {
    const float4* in  = (const float4*)d_in[0];
    float4*       out = (float4*)d_out;
    float4*       ws  = (float4*)d_ws;   // eroded intermediate (128 MiB)

    dim3 grid(512 / TW, (512 + TH - 1) / TH, 16);   // 16 x 22 x 16 = 5632 blocks

    morph<true ><<<grid, 256, 0, stream>>>(in, ws);   // erosion
    morph<false><<<grid, 256, 0, stream>>>(ws, out);  // dilation
}

// Round 6
// 367.150 us; speedup vs baseline: 1.0272x; 1.0272x over previous
//
#include <hip/hip_runtime.h>
#include <math.h>

// Morphological opening, 10x10 flat kernel, SAME pad (window [i-4, i+5]).
// NHWC fp32 [16,512,512,8]. Two fused kernels:
//   erosion  (min): in -> ws      dilation (max): ws -> out (pads -inf)
// Per block (22x32 px output tile):
//   phase 1: H-op (vertical), GLOBAL->sM. Coalesced: lanes = consecutive f4
//            cols, 17 row-taps -> run of 8 output rows (prefix/suffix trick).
//   phase 2: W-op (horizontal), sM->sOut (LDS). Run of 8 px per thread.
//   phase 3: coalesced copy sOut->GLOBAL (1 KB contiguous per wave-store).
// R1-R5 evidence: any pass with a scattered (32 B-granule) global side runs
// ~120-185 us; coalesced-both runs ~50 us (R1 pass_h, inferred). This round
// removes the last scattered side (phase-2 stores) via the sOut staging.
// LDS = 22*83*16 + 22*65*16 = 52.1 KB -> 3 blocks/CU.

#define W_F4   1024              // 512 px * 2 f4 (8 ch)
#define IMG_F4 (512 * W_F4)
#define TH     22                // output rows per tile
#define TW     32                // output px per tile
#define MCOLS  82                // (TW + 9) px * 2 f4
#define S_M    83                // sM row stride (f4)
#define S_O    65                // sOut row stride (f4)

__device__ __forceinline__ float4 f4min(float4 a, float4 b) {
    return make_float4(fminf(a.x,b.x), fminf(a.y,b.y), fminf(a.z,b.z), fminf(a.w,b.w));
}
__device__ __forceinline__ float4 f4max(float4 a, float4 b) {
    return make_float4(fmaxf(a.x,b.x), fmaxf(a.y,b.y), fmaxf(a.z,b.z), fmaxf(a.w,b.w));
}
template <bool IS_MIN>
__device__ __forceinline__ float4 f4op(float4 a, float4 b) {
    return IS_MIN ? f4min(a, b) : f4max(a, b);
}

template <bool IS_MIN>
__global__ __launch_bounds__(256, 3) void morph(const float4* __restrict__ in,
                                                float4* __restrict__ out) {
    __shared__ float4 sM  [TH * S_M];    // 22*83*16 = 29,216 B
    __shared__ float4 sOut[TH * S_O];    // 22*65*16 = 22,880 B  (52.1 KB total)

    const float  IDENT  = IS_MIN ? INFINITY : -INFINITY;
    const float4 ident4 = make_float4(IDENT, IDENT, IDENT, IDENT);

    const int t  = threadIdx.x;
    const int h0 = blockIdx.y * TH;      // last band ragged (h0 = 506)
    const int w0 = blockIdx.x * TW;

    const float4* img  = in  + (size_t)blockIdx.z * IMG_F4;
    float4*       oimg = out + (size_t)blockIdx.z * IMG_F4;

    // ---- phase 1: vertical op, global -> sM.  246 tasks: c in [0,82), p in [0,3) ----
    if (t < 3 * MCOLS) {
        const int c = t % MCOLS;         // f4 col within sM (lanes contiguous)
        const int p = t / MCOLS;         // run of 8 output rows: p*8 + i
        const int colf4 = w0 * 2 - 8 + c;
        const bool colok = (colf4 >= 0) & (colf4 < W_F4);

        float4 v[17];
#pragma unroll
        for (int q = 0; q < 17; q++) {   // input rows h0 + p*8 - 4 + q
            int h = h0 + p * 8 - 4 + q;
            bool ok = colok & (h >= 0) & (h < 512);
            v[q] = ok ? img[(size_t)h * W_F4 + colf4] : ident4;
        }
        float4 L[9]; L[8] = v[8];
#pragma unroll
        for (int i = 7; i >= 0; i--) L[i] = f4op<IS_MIN>(v[i], L[i + 1]);
        float4 rr = v[9];
#pragma unroll
        for (int i = 0; i < 8; i++) {
            if (i > 0) rr = f4op<IS_MIN>(rr, v[9 + i]);
            int o = p * 8 + i;
            if (o < TH) sM[o * S_M + c] = f4op<IS_MIN>(L[i], rr);
        }
    }
    __syncthreads();

    // ---- phase 2: horizontal op, sM -> sOut.  176 tasks: c4 x 22 rows x 4 runs ----
    if (t < 2 * TH * (TW / 8)) {
        const int c4 = t & 1;
        const int r  = (t >> 1) % TH;
        const int p  = (t >> 1) / TH;    // 0..3, run of 8 output px

        float4 v[17];
#pragma unroll
        for (int q = 0; q < 17; q++)     // sM px p*8+q  (max f4 idx 81 < 82)
            v[q] = sM[r * S_M + (p * 8 + q) * 2 + c4];
        float4 L[9]; L[8] = v[8];
#pragma unroll
        for (int i = 7; i >= 0; i--) L[i] = f4op<IS_MIN>(v[i], L[i + 1]);
        float4 rr = v[9];
#pragma unroll
        for (int i = 0; i < 8; i++) {
            if (i > 0) rr = f4op<IS_MIN>(rr, v[9 + i]);
            sOut[r * S_O + (p * 8 + i) * 2 + c4] = f4op<IS_MIN>(L[i], rr);
        }
    }
    __syncthreads();

    // ---- phase 3: coalesced copy sOut -> global (lanes = consecutive f4) ----
    for (int idx = t; idx < TH * 64; idx += 256) {
        int r = idx >> 6;                // wave covers one full 1 KB row chunk
        int c = idx & 63;
        int hr = h0 + r;
        if (hr < 512)
            oimg[(size_t)hr * W_F4 + (size_t)w0 * 2 + c] = sOut[r * S_O + c];
    }
}

extern "C" void kernel_launch(void* const* d_in, const int* in_sizes, int n_in,
                              void* d_out, int out_size, void* d_ws, size_t ws_size,
                              hipStream_t stream) {
    const float4* in  = (const float4*)d_in[0];
    float4*       out = (float4*)d_out;
    float4*       ws  = (float4*)d_ws;   // eroded intermediate (128 MiB)

    dim3 grid(512 / TW, (512 + TH - 1) / TH, 16);   // 16 x 24 x 16 = 6144 blocks

    morph<true ><<<grid, 256, 0, stream>>>(in, ws);   // erosion
    morph<false><<<grid, 256, 0, stream>>>(ws, out);  // dilation
}